// Round 1
// baseline (9745.944 us; speedup 1.0000x reference)
//
#include <hip/hip_runtime.h>
#include <stdint.h>

#define NB 512   // batch
#define NT 32    // time steps
#define NIN 8    // input feats
#define NIN1 9   // + y_prev
#define NH 64    // hidden
#define NP 256   // particles

struct FKeys { uint32_t a[NT]; uint32_t b[NT]; };

// ---------------- Threefry-2x32-20 (exact JAX semantics) ----------------
__host__ __device__ __forceinline__ void tfr(uint32_t& x0, uint32_t& x1, int r) {
  x0 += x1; x1 = (x1 << r) | (x1 >> (32 - r)); x1 ^= x0;
}

__host__ __device__ __forceinline__ void threefry2x32(uint32_t k0, uint32_t k1,
                                                      uint32_t& x0, uint32_t& x1) {
  uint32_t k2 = k0 ^ k1 ^ 0x1BD11BDAu;
  x0 += k0; x1 += k1;
  tfr(x0,x1,13); tfr(x0,x1,15); tfr(x0,x1,26); tfr(x0,x1,6);
  x0 += k1; x1 += k2 + 1u;
  tfr(x0,x1,17); tfr(x0,x1,29); tfr(x0,x1,16); tfr(x0,x1,24);
  x0 += k2; x1 += k0 + 2u;
  tfr(x0,x1,13); tfr(x0,x1,15); tfr(x0,x1,26); tfr(x0,x1,6);
  x0 += k0; x1 += k1 + 3u;
  tfr(x0,x1,17); tfr(x0,x1,29); tfr(x0,x1,16); tfr(x0,x1,24);
  x0 += k1; x1 += k2 + 4u;
  tfr(x0,x1,13); tfr(x0,x1,15); tfr(x0,x1,26); tfr(x0,x1,6);
  x0 += k2; x1 += k0 + 5u;
}

// bits -> uniform(nextafter(-1,0), 1) -> sqrt(2)*erfinv  (XLA f32 path)
__device__ __forceinline__ float normal_from_bits(uint32_t bits) {
  float f = __uint_as_float((bits >> 9) | 0x3f800000u) - 1.0f;  // [0,1)
  const float lo = -0.99999994f;                                 // nextafter(-1,0)
  float u = fmaxf(lo, fmaf(f, 2.0f, lo));                        // (hi-lo) rounds to 2.0f
  float w = -log1pf(-u * u);
  float p;
  if (w < 5.0f) {
    w -= 2.5f;
    p = 2.81022636e-08f;
    p = fmaf(p, w, 3.43273939e-07f);
    p = fmaf(p, w, -3.5233877e-06f);
    p = fmaf(p, w, -4.39150654e-06f);
    p = fmaf(p, w, 0.00021858087f);
    p = fmaf(p, w, -0.00125372503f);
    p = fmaf(p, w, -0.00417768164f);
    p = fmaf(p, w, 0.246640727f);
    p = fmaf(p, w, 1.50140941f);
  } else {
    w = sqrtf(w) - 3.0f;
    p = -0.000200214257f;
    p = fmaf(p, w, 0.000100950558f);
    p = fmaf(p, w, 0.00134934322f);
    p = fmaf(p, w, -0.00367342844f);
    p = fmaf(p, w, 0.00573950773f);
    p = fmaf(p, w, -0.0076224613f);
    p = fmaf(p, w, 0.00943887047f);
    p = fmaf(p, w, 1.00167406f);
    p = fmaf(p, w, 2.83297682f);
  }
  return 1.41421356f * (p * u);
}

// ---------------- main particle-filter kernel: one block per batch elem ----------------
__global__ __launch_bounds__(256, 2)
void pf_main(const float* __restrict__ input_data, const float* __restrict__ y_prev,
             const float* __restrict__ Wv, const float* __restrict__ bv,
             const float* __restrict__ W_ih, const float* __restrict__ W_hh,
             const float* __restrict__ b_ih, const float* __restrict__ b_hh,
             const float* __restrict__ Wp, const float* __restrict__ bp,
             const float* __restrict__ Wf, const float* __restrict__ bf,
             float* __restrict__ out, float* __restrict__ cbuf, float* __restrict__ gw,
             FKeys fk)
{
  // h state transposed [H][P]: column access by lane -> 2-way bank alias (free)
  __shared__ float hBuf[NH * NP];                 // 64 KB
  __shared__ float xg_s[4 * NH];                  // x-part of gates + biases
  __shared__ __align__(16) float proj_s[NP];
  __shared__ float wsum_s[NP];                    // sum_t exp(logpdf) per sorted slot
  __shared__ float red_s[4][NH];
  __shared__ float hmean_s[NH];
  __shared__ float std_s[NH];
  __shared__ float xs_s[16];

  const int tid  = threadIdx.x;     // == particle slot p
  const int b    = blockIdx.x;
  const int lane = tid & 63;
  const int wid  = tid >> 6;

  #pragma unroll
  for (int j = 0; j < NH; ++j) hBuf[j * NP + tid] = 0.0f;
  wsum_s[tid] = 0.0f;

  // hoist per-thread constants
  float wih_r[NIN1];
  #pragma unroll
  for (int i = 0; i < NIN1; ++i) wih_r[i] = W_ih[tid * NIN1 + i];
  const float bihh = b_ih[tid] + b_hh[tid];
  const float bv_r = (tid < NH) ? bv[tid] : 0.0f;
  const float bf0  = bf[0];
  const float bp0  = bp[0];
  const uint32_t xbase  = ((uint32_t)(tid & 127) << 15) | ((uint32_t)b << 6);
  const bool hihalf = (tid >= 128);

  __syncthreads();

  for (int t = 0; t < NT; ++t) {
    // ---- A: load x_t, read own h column, cross-particle partial sums ----
    if (tid < NIN) xs_s[tid] = input_data[(b * NT + t) * NIN + tid];
    if (tid == NIN) xs_s[NIN] = y_prev[b * NT + t];

    float h_reg[NH];
    #pragma unroll
    for (int j = 0; j < NH; ++j) h_reg[j] = hBuf[j * NP + tid];

    #pragma unroll
    for (int j = 0; j < NH; ++j) {
      float s = h_reg[j];
      s += __shfl_xor(s, 32, 64);
      s += __shfl_xor(s, 16, 64);
      s += __shfl_xor(s, 8, 64);
      s += __shfl_xor(s, 4, 64);
      s += __shfl_xor(s, 2, 64);
      s += __shfl_xor(s, 1, 64);
      if (lane == 0) red_s[wid][j] = s;
    }
    __syncthreads();

    // ---- B: hidden_mean + x-part of gates ----
    if (tid < NH)
      hmean_s[tid] = (red_s[0][tid] + red_s[1][tid] + red_s[2][tid] + red_s[3][tid]) * (1.0f / NP);
    {
      float a = bihh;
      #pragma unroll
      for (int i = 0; i < NIN1; ++i) a = fmaf(xs_s[i], wih_r[i], a);
      xg_s[tid] = a;
    }
    __syncthreads();

    // ---- C: std = softplus(concat(x, hmean) @ Wv.T + bv) ----
    if (tid < NH) {
      float v = bv_r;
      const float* wvr = Wv + tid * (NIN1 + NH);
      #pragma unroll
      for (int i = 0; i < NIN1; ++i) v = fmaf(xs_s[i], wvr[i], v);
      #pragma unroll
      for (int k = 0; k < NH; ++k) v = fmaf(hmean_s[k], wvr[NIN1 + k], v);
      std_s[tid] = fmaxf(v, 0.0f) + log1pf(expf(-fabsf(v)));  // logaddexp(v,0)
    }
    __syncthreads();

    // ---- D: LSTM cell + reparam noise; accumulate proj & logpdf on the fly ----
    float proj_acc = bf0;
    float lp_acc = 0.0f;
    const uint32_t fk0 = fk.a[t], fk1 = fk.b[t];
    for (int k = 0; k < NH; ++k) {
      const float* wi  = W_hh + (0 * NH + k) * NH;
      const float* wf_ = W_hh + (1 * NH + k) * NH;
      const float* wg  = W_hh + (2 * NH + k) * NH;
      const float* wo  = W_hh + (3 * NH + k) * NH;
      float ai = xg_s[k], af = xg_s[NH + k], ag = xg_s[2 * NH + k], ao = xg_s[3 * NH + k];
      #pragma unroll
      for (int j = 0; j < NH; ++j) {
        ai = fmaf(h_reg[j], wi[j],  ai);
        af = fmaf(h_reg[j], wf_[j], af);
        ag = fmaf(h_reg[j], wg[j],  ag);
        ao = fmaf(h_reg[j], wo[j],  ao);
      }
      const size_t cidx = ((size_t)b * NH + k) * NP + tid;   // coalesced per k
      float cold = (t == 0) ? 0.0f : cbuf[cidx];
      float si = 1.0f / (1.0f + expf(-ai));
      float sf = 1.0f / (1.0f + expf(-af));
      float so = 1.0f / (1.0f + expf(-ao));
      float cn = sf * cold + si * tanhf(ag);
      cbuf[cidx] = cn;                                        // c is NOT sorted
      float hl = so * tanhf(cn);
      uint32_t x0 = xbase | (uint32_t)k;                      // flat idx (p,b,k); pair (m, m+2^22)
      uint32_t x1 = x0 + (1u << 22);
      threefry2x32(fk0, fk1, x0, x1);
      float eps = normal_from_bits(hihalf ? x1 : x0);
      float hrep = fmaf(eps, std_s[k], hl);
      hBuf[k * NP + tid] = hrep;                              // own column, pre-sort
      proj_acc = fmaf(hrep, Wf[k], proj_acc);
      lp_acc   = fmaf(hrep, Wp[k], lp_acc);
    }

    proj_s[tid] = proj_acc;
    __syncthreads();

    // ---- stable rank (ascending, ties by index) == jnp.argsort position ----
    int rank = 0;
    const float myv = proj_acc;
    const float4* p4 = (const float4*)proj_s;
    #pragma unroll 8
    for (int q4 = 0; q4 < NP / 4; ++q4) {
      float4 v = p4[q4];
      int qb = q4 * 4;
      rank += (v.x < myv || (v.x == myv && qb + 0 < tid)) ? 1 : 0;
      rank += (v.y < myv || (v.y == myv && qb + 1 < tid)) ? 1 : 0;
      rank += (v.z < myv || (v.z == myv && qb + 2 < tid)) ? 1 : 0;
      rank += (v.w < myv || (v.w == myv && qb + 3 < tid)) ? 1 : 0;
    }

    // ---- logpdf at sorted slot; accumulate exp into wsum by slot ----
    float xpart = bp0;
    #pragma unroll
    for (int i = 0; i < NIN1; ++i) xpart = fmaf(xs_s[i], Wp[NH + i], xpart);
    wsum_s[rank] += expf(lp_acc + xpart);   // ranks are a permutation -> race-free

    // ---- in-place sort scatter: read own column to regs, barrier, write at rank ----
    #pragma unroll
    for (int j = 0; j < NH; ++j) h_reg[j] = hBuf[j * NP + tid];
    __syncthreads();
    #pragma unroll
    for (int j = 0; j < NH; ++j) hBuf[j * NP + rank] = h_reg[j];
    __syncthreads();
  }

  // ---- epilogue: y_pred[b] = mean_p(h_fin) @ Wf + bf ----
  #pragma unroll
  for (int j = 0; j < NH; ++j) {
    float s = hBuf[j * NP + tid];
    s += __shfl_xor(s, 32, 64);
    s += __shfl_xor(s, 16, 64);
    s += __shfl_xor(s, 8, 64);
    s += __shfl_xor(s, 4, 64);
    s += __shfl_xor(s, 2, 64);
    s += __shfl_xor(s, 1, 64);
    if (lane == 0) red_s[wid][j] = s;
  }
  __syncthreads();
  if (tid < NH) {
    float hm = (red_s[0][tid] + red_s[1][tid] + red_s[2][tid] + red_s[3][tid]) * (1.0f / NP);
    float contrib = hm * Wf[tid];
    contrib += __shfl_xor(contrib, 32, 64);
    contrib += __shfl_xor(contrib, 16, 64);
    contrib += __shfl_xor(contrib, 8, 64);
    contrib += __shfl_xor(contrib, 4, 64);
    contrib += __shfl_xor(contrib, 2, 64);
    contrib += __shfl_xor(contrib, 1, 64);
    if (tid == 0) out[b] = contrib + bf0;
  }
  // per-slot exp-sums -> global for the cross-batch weights reduction
  gw[(size_t)tid * NB + b] = wsum_s[tid];
}

// weights[i] = (1/256) * sum_{j<256} gw[(i>>1)*512 + (i&1)*256 + j]
// (faithful to the reference's particle-major reshape(-1).reshape(B,P))
__global__ __launch_bounds__(64, 1)
void pf_weights(const float* __restrict__ gw, float* __restrict__ out) {
  int i = blockIdx.x;
  int lane = threadIdx.x;
  const float* src = gw + ((size_t)(i >> 1)) * NB + (size_t)(i & 1) * NP;
  float4 v = ((const float4*)src)[lane];
  float s = (v.x + v.y) + (v.z + v.w);
  s += __shfl_xor(s, 32, 64);
  s += __shfl_xor(s, 16, 64);
  s += __shfl_xor(s, 8, 64);
  s += __shfl_xor(s, 4, 64);
  s += __shfl_xor(s, 2, 64);
  s += __shfl_xor(s, 1, 64);
  if (lane == 0) out[NB + i] = s * (1.0f / NP);
}

extern "C" void kernel_launch(void* const* d_in, const int* in_sizes, int n_in,
                              void* d_out, int out_size, void* d_ws, size_t ws_size,
                              hipStream_t stream) {
  (void)in_sizes; (void)n_in; (void)out_size; (void)ws_size;
  const float* input_data = (const float*)d_in[0];
  const float* y_prev     = (const float*)d_in[1];
  const float* Wv         = (const float*)d_in[2];
  const float* bv         = (const float*)d_in[3];
  const float* W_ih       = (const float*)d_in[4];
  const float* W_hh       = (const float*)d_in[5];
  const float* b_ih       = (const float*)d_in[6];
  const float* b_hh       = (const float*)d_in[7];
  const float* Wp         = (const float*)d_in[8];
  const float* bp         = (const float*)d_in[9];
  const float* Wf         = (const float*)d_in[10];
  const float* bf         = (const float*)d_in[11];
  float* out  = (float*)d_out;
  float* cbuf = (float*)d_ws;                          // [B][H][P] f32 = 33.5 MB
  float* gw   = cbuf + (size_t)NB * NH * NP;           // [P][B] f32 = 512 KB

  // host-side fold_in keys: threefry2x32(key=(0,1234), count=(0,t))
  FKeys fk;
  for (int t = 0; t < NT; ++t) {
    uint32_t x0 = 0u, x1 = (uint32_t)t;
    threefry2x32(0u, 1234u, x0, x1);
    fk.a[t] = x0; fk.b[t] = x1;
  }

  pf_main<<<dim3(NB), dim3(NP), 0, stream>>>(
      input_data, y_prev, Wv, bv, W_ih, W_hh, b_ih, b_hh, Wp, bp, Wf, bf,
      out, cbuf, gw, fk);
  pf_weights<<<dim3(NB), dim3(64), 0, stream>>>(gw, out);
}